// Round 1
// baseline (2266.929 us; speedup 1.0000x reference)
//
#include <hip/hip_runtime.h>
#include <hip/hip_bf16.h>
#include <math.h>

#define BQ_RADIUS 0.15f
#define NSAMPLE 32
#define BN_EPS 1e-5f

constexpr int B_ = 2, N_ = 8192, C_ = 64, C1_ = 128, C2_ = 128, CIN_ = 67;

// ---------------- Kernel A: ball query (first-K-hits-in-index-order) -------
// One thread per query point; wave-uniform scan over j with early exit when
// every lane in the wave has found K hits. p loads are wave-uniform -> scalar.
__global__ __launch_bounds__(64) void ball_query_kernel(
    const float* __restrict__ p, int* __restrict__ idx)
{
    int gid = blockIdx.x * 64 + threadIdx.x;   // 0 .. B*N-1  (N multiple of 64)
    int b = gid >> 13;                         // / 8192
    int i = gid & (N_ - 1);
    const float* pb = p + (size_t)b * N_ * 3;
    float qx = pb[3 * i], qy = pb[3 * i + 1], qz = pb[3 * i + 2];
    int* out = idx + (size_t)gid * NSAMPLE;
    const float r2 = BQ_RADIUS * BQ_RADIUS;
    int cnt = 0, first = -1;
    for (int j = 0; j < N_; ++j) {
        float dx = pb[3 * j]     - qx;
        float dy = pb[3 * j + 1] - qy;
        float dz = pb[3 * j + 2] - qz;
        float d2 = dx * dx + dy * dy + dz * dz;
        if (d2 < r2 && cnt < NSAMPLE) {
            if (cnt == 0) first = j;
            out[cnt] = j;
            ++cnt;
        }
        if (__all(cnt >= NSAMPLE)) break;      // whole wave done -> stop scan
    }
    for (int k = cnt; k < NSAMPLE; ++k) out[k] = first;  // pad with first hit
}

// ------------- Kernel B: fused gather + conv1+BN+ReLU + conv2+BN + max -----
// One block per (b,n). 128 threads; thread t owns output channel t.
__global__ __launch_bounds__(128) void fused_mlp_kernel(
    const float* __restrict__ p, const float* __restrict__ f,
    const int* __restrict__ idx,
    const float* __restrict__ W1,
    const float* __restrict__ g1, const float* __restrict__ bb1,
    const float* __restrict__ m1, const float* __restrict__ v1,
    const float* __restrict__ W2,
    const float* __restrict__ g2, const float* __restrict__ bb2,
    const float* __restrict__ m2, const float* __restrict__ v2,
    float* __restrict__ out)
{
    __shared__ float xs[CIN_][NSAMPLE + 1];   // +1 pad: bank-conflict-free
    __shared__ float hs[C1_][NSAMPLE + 1];
    __shared__ int sidx[NSAMPLE];

    int bn = blockIdx.x;                      // 0 .. B*N-1
    int b = bn >> 13;
    int n = bn & (N_ - 1);
    int t = threadIdx.x;

    const float* pb = p + (size_t)b * N_ * 3;
    const float* fb = f + (size_t)b * C_ * N_;

    if (t < NSAMPLE) sidx[t] = idx[(size_t)bn * NSAMPLE + t];
    __syncthreads();

    // dp channels 0..2
    if (t < NSAMPLE) {
        int j = sidx[t];
        xs[0][t] = pb[3 * j]     - pb[3 * n];
        xs[1][t] = pb[3 * j + 1] - pb[3 * n + 1];
        xs[2][t] = pb[3 * j + 2] - pb[3 * n + 2];
    }
    // fj channels 3..66 : 64*32 elements, gathered from f
    for (int i2 = t; i2 < C_ * NSAMPLE; i2 += 128) {
        int c = i2 >> 5, k = i2 & 31;
        xs[3 + c][k] = fb[(size_t)c * N_ + sidx[k]];
    }
    __syncthreads();

    // ---- conv1 (67 -> 128) ----
    float acc[NSAMPLE];
    #pragma unroll
    for (int k = 0; k < NSAMPLE; ++k) acc[k] = 0.f;
    const float* w1r = W1 + t * CIN_;
    for (int c = 0; c < CIN_; ++c) {
        float w = w1r[c];
        #pragma unroll
        for (int k = 0; k < NSAMPLE; ++k) acc[k] = fmaf(w, xs[c][k], acc[k]);
    }
    float sc = g1[t] * rsqrtf(v1[t] + BN_EPS);
    float sh = bb1[t] - m1[t] * sc;
    #pragma unroll
    for (int k = 0; k < NSAMPLE; ++k)
        hs[t][k] = fmaxf(fmaf(acc[k], sc, sh), 0.f);
    __syncthreads();

    // ---- conv2 (128 -> 128) + max over k ----
    #pragma unroll
    for (int k = 0; k < NSAMPLE; ++k) acc[k] = 0.f;
    const float* w2r = W2 + t * C1_;
    for (int c = 0; c < C1_; ++c) {
        float w = w2r[c];
        #pragma unroll
        for (int k = 0; k < NSAMPLE; ++k) acc[k] = fmaf(w, hs[c][k], acc[k]);
    }
    sc = g2[t] * rsqrtf(v2[t] + BN_EPS);
    sh = bb2[t] - m2[t] * sc;
    float mx = -INFINITY;
    #pragma unroll
    for (int k = 0; k < NSAMPLE; ++k) mx = fmaxf(mx, fmaf(acc[k], sc, sh));
    mx = fmaxf(mx, 0.f);                      // max(relu(y)) == relu(max(y))
    out[((size_t)(b * C2_ + t)) * N_ + n] = mx;
}

extern "C" void kernel_launch(void* const* d_in, const int* in_sizes, int n_in,
                              void* d_out, int out_size, void* d_ws, size_t ws_size,
                              hipStream_t stream) {
    const float* p   = (const float*)d_in[0];
    const float* f   = (const float*)d_in[1];
    const float* W1  = (const float*)d_in[2];
    const float* g1  = (const float*)d_in[3];
    const float* bb1 = (const float*)d_in[4];
    const float* m1  = (const float*)d_in[5];
    const float* v1  = (const float*)d_in[6];
    const float* W2  = (const float*)d_in[7];
    const float* g2  = (const float*)d_in[8];
    const float* bb2 = (const float*)d_in[9];
    const float* m2  = (const float*)d_in[10];
    const float* v2  = (const float*)d_in[11];
    float* out = (float*)d_out;

    int* idx = (int*)d_ws;                    // B*N*K ints = 2 MB scratch

    ball_query_kernel<<<(B_ * N_) / 64, 64, 0, stream>>>(p, idx);
    fused_mlp_kernel<<<B_ * N_, 128, 0, stream>>>(
        p, f, idx, W1, g1, bb1, m1, v1, W2, g2, bb2, m2, v2, out);
}

// Round 2
// 241.918 us; speedup vs baseline: 9.3707x; 9.3707x over previous
//
#include <hip/hip_runtime.h>
#include <math.h>

#define NSAMPLE 32
constexpr int B_ = 2, N_ = 8192, C_ = 64, C1_ = 128, C2_ = 128, CIN_ = 67;
constexpr int KP = 96;            // padded Cin for GEMM1 (3 k-steps of 32)
constexpr int XPAD = 104;         // XT row pad (odd*8 -> 2-way LDS aliasing max)
constexpr int HPAD = 136;         // HT row pad
constexpr float BQ_R2 = 0.15f * 0.15f;
constexpr float EPS_ = 1e-5f;

typedef __attribute__((ext_vector_type(8))) short bf16x8;   // 8 bf16 = 4 VGPR
typedef __attribute__((ext_vector_type(4))) short short4v;
typedef __attribute__((ext_vector_type(4))) float f32x4;

__device__ __forceinline__ short f2bf(float x) {
    union { float f; unsigned u; } v; v.f = x;
    return (short)((v.u + 0x7FFFu + ((v.u >> 16) & 1u)) >> 16);   // RNE
}

// ---------------- ball query: one WAVE per query point --------------------
__global__ __launch_bounds__(256) void ball_query_kernel(
    const float* __restrict__ p, int* __restrict__ idx)
{
    int wid = (blockIdx.x * 256 + threadIdx.x) >> 6;   // 0..B*N-1
    int lane = threadIdx.x & 63;
    int b = wid >> 13, n = wid & (N_ - 1);
    const float* pb = p + (size_t)b * N_ * 3;
    float qx = pb[3 * n], qy = pb[3 * n + 1], qz = pb[3 * n + 2];
    int* out = idx + (size_t)wid * NSAMPLE;

    int cnt = 0, first = -1;
    for (int j0 = 0; j0 < N_; j0 += 64) {
        int j = j0 + lane;
        float dx = pb[3 * j] - qx, dy = pb[3 * j + 1] - qy, dz = pb[3 * j + 2] - qz;
        float d2 = __fadd_rn(__fadd_rn(__fmul_rn(dx, dx), __fmul_rn(dy, dy)),
                             __fmul_rn(dz, dz));
        bool hit = d2 < BQ_R2;
        unsigned long long m = __ballot(hit);
        if (hit) {
            int pos = cnt + __popcll(m & ((1ull << lane) - 1ull));
            if (pos < NSAMPLE) out[pos] = j;
        }
        if (first < 0 && m) first = j0 + (__ffsll((long long)m) - 1);
        cnt += __popcll(m);
        if (cnt >= NSAMPLE) break;   // wave-uniform
    }
    for (int k2 = cnt + lane; k2 < NSAMPLE; k2 += 64) out[k2] = first;
}

// -------- transpose f [B,C,N] fp32 -> fT [B*N, 64] bf16 (rows = samples) ---
__global__ __launch_bounds__(256) void transpose_f_kernel(
    const float* __restrict__ f, short* __restrict__ fT)
{
    int g = blockIdx.x * 256 + threadIdx.x;            // 0..B*N-1
    int b = g >> 13, n = g & (N_ - 1);
    const float* fb = f + (size_t)b * C_ * N_ + n;     // lanes: consecutive n -> coalesced
    short* row = fT + (size_t)g * C_;
    for (int c0 = 0; c0 < C_; c0 += 8) {
        bf16x8 v;
        #pragma unroll
        for (int c = 0; c < 8; ++c) v[c] = f2bf(fb[(size_t)(c0 + c) * N_]);
        *(bf16x8*)&row[c0] = v;                        // 16B store
    }
}

// -------- weight / BN prep: bf16 padded W1p[128][96], W2p[128][128] --------
// XT k-layout: [0..2]=dp, [3..7]=0, [8..71]=f channels 0..63, [72..95]=0
__global__ __launch_bounds__(128) void weight_prep_kernel(
    const float* __restrict__ W1,
    const float* __restrict__ g1, const float* __restrict__ b1,
    const float* __restrict__ m1, const float* __restrict__ v1,
    const float* __restrict__ W2,
    const float* __restrict__ g2, const float* __restrict__ b2,
    const float* __restrict__ m2, const float* __restrict__ v2,
    short* __restrict__ W1p, short* __restrict__ W2p, float* __restrict__ bn)
{
    int t = threadIdx.x;
    short* r1 = W1p + t * KP;
    #pragma unroll
    for (int k = 0; k < 3; ++k) r1[k] = f2bf(W1[t * CIN_ + k]);
    #pragma unroll
    for (int k = 3; k < 8; ++k) r1[k] = 0;
    for (int c = 0; c < 64; ++c) r1[8 + c] = f2bf(W1[t * CIN_ + 3 + c]);
    #pragma unroll
    for (int k = 72; k < KP; ++k) r1[k] = 0;
    short* r2 = W2p + t * C1_;
    for (int c = 0; c < C1_; ++c) r2[c] = f2bf(W2[t * C1_ + c]);
    float s1 = g1[t] * rsqrtf(v1[t] + EPS_);
    bn[t] = s1;            bn[128 + t] = b1[t] - m1[t] * s1;
    float s2 = g2[t] * rsqrtf(v2[t] + EPS_);
    bn[256 + t] = s2;      bn[384 + t] = b2[t] - m2[t] * s2;
}

// -------- fused gather + GEMM1 + BN/ReLU + GEMM2 + BN + max ----------------
// Block: 256 thr (4 waves), 4 points (128 sample-columns).
// Wave w owns output quadrant rows (w&1)*64..+63  x  cols (w>>1)*64..+63.
__global__ __launch_bounds__(256) void fused_mfma_kernel(
    const float* __restrict__ p, const int* __restrict__ idx,
    const short* __restrict__ fT, const short* __restrict__ W1p,
    const short* __restrict__ W2p, const float* __restrict__ bn,
    float* __restrict__ out)
{
    __shared__ short XT[128][XPAD];    // [col][k]  B-operand of GEMM1 (transposed)
    __shared__ short HT[128][HPAD];    // [col][c]  B-operand of GEMM2
    __shared__ float sBN[4][128];

    int tid = threadIdx.x;
    int bk = blockIdx.x;               // 0..4095
    int b = bk >> 11;                  // 2048 blocks per batch
    int n0 = (bk & 2047) * 4;
    int lane = tid & 63, w = tid >> 6;
    int lr = lane & 15, lq = lane >> 4;

    // zero XT (covers the k-pad lanes) + load BN vectors
    {
        short4v z = {0, 0, 0, 0};
        for (int i2 = tid; i2 < 128 * XPAD / 4; i2 += 256)
            ((short4v*)&XT[0][0])[i2] = z;
    }
    if (tid < 128) {
        sBN[0][tid] = bn[tid];       sBN[1][tid] = bn[128 + tid];
        sBN[2][tid] = bn[256 + tid]; sBN[3][tid] = bn[384 + tid];
    }
    __syncthreads();

    // ---- stage XT: 8 threads per column ----
    const float* pb = p + (size_t)b * N_ * 3;
    #pragma unroll
    for (int pass = 0; pass < 4; ++pass) {
        int col = pass * 32 + (tid >> 3);
        int part = tid & 7;
        int pp = col >> 5, k = col & 31;
        int j = idx[((size_t)((b << 13) | (n0 + pp))) * NSAMPLE + k];
        *(bf16x8*)&XT[col][8 + part * 8] =
            *(const bf16x8*)&fT[((size_t)(b << 13) + j) * C_ + part * 8];
        if (part == 0) {
            int n = n0 + pp;
            XT[col][0] = f2bf(pb[3 * j]     - pb[3 * n]);
            XT[col][1] = f2bf(pb[3 * j + 1] - pb[3 * n + 1]);
            XT[col][2] = f2bf(pb[3 * j + 2] - pb[3 * n + 2]);
        }
    }
    __syncthreads();

    int wr = (w & 1) * 64;   // row (out-channel) base
    int wc = (w >> 1) * 64;  // col (sample) base

    // ---- GEMM1: [128x96] x [96x128] ----
    f32x4 acc[4][4];
    #pragma unroll
    for (int m = 0; m < 4; ++m)
        #pragma unroll
        for (int nt = 0; nt < 4; ++nt) acc[m][nt] = (f32x4){0.f, 0.f, 0.f, 0.f};
    #pragma unroll
    for (int ks = 0; ks < 3; ++ks) {
        bf16x8 a[4];
        #pragma unroll
        for (int m = 0; m < 4; ++m)
            a[m] = *(const bf16x8*)&W1p[(wr + m * 16 + lr) * KP + ks * 32 + lq * 8];
        #pragma unroll
        for (int nt = 0; nt < 4; ++nt) {
            bf16x8 bf = *(const bf16x8*)&XT[wc + nt * 16 + lr][ks * 32 + lq * 8];
            #pragma unroll
            for (int m = 0; m < 4; ++m)
                acc[m][nt] = __builtin_amdgcn_mfma_f32_16x16x32_bf16(a[m], bf, acc[m][nt], 0, 0, 0);
        }
    }

    // ---- BN1 + ReLU -> HT (bf16, transposed) ----
    #pragma unroll
    for (int m = 0; m < 4; ++m) {
        int rb = wr + m * 16 + lq * 4;
        float s0 = sBN[0][rb], s1 = sBN[0][rb + 1], s2 = sBN[0][rb + 2], s3 = sBN[0][rb + 3];
        float h0 = sBN[1][rb], h1 = sBN[1][rb + 1], h2 = sBN[1][rb + 2], h3 = sBN[1][rb + 3];
        #pragma unroll
        for (int nt = 0; nt < 4; ++nt) {
            int col = wc + nt * 16 + lr;
            short4v hv;
            hv[0] = f2bf(fmaxf(fmaf(acc[m][nt][0], s0, h0), 0.f));
            hv[1] = f2bf(fmaxf(fmaf(acc[m][nt][1], s1, h1), 0.f));
            hv[2] = f2bf(fmaxf(fmaf(acc[m][nt][2], s2, h2), 0.f));
            hv[3] = f2bf(fmaxf(fmaf(acc[m][nt][3], s3, h3), 0.f));
            *(short4v*)&HT[col][rb] = hv;
        }
    }
    __syncthreads();

    // ---- GEMM2: [128x128] x [128x128] ----
    f32x4 acc2[4][4];
    #pragma unroll
    for (int m = 0; m < 4; ++m)
        #pragma unroll
        for (int nt = 0; nt < 4; ++nt) acc2[m][nt] = (f32x4){0.f, 0.f, 0.f, 0.f};
    #pragma unroll
    for (int ks = 0; ks < 4; ++ks) {
        bf16x8 a[4];
        #pragma unroll
        for (int m = 0; m < 4; ++m)
            a[m] = *(const bf16x8*)&W2p[(wr + m * 16 + lr) * C1_ + ks * 32 + lq * 8];
        #pragma unroll
        for (int nt = 0; nt < 4; ++nt) {
            bf16x8 bf = *(const bf16x8*)&HT[wc + nt * 16 + lr][ks * 32 + lq * 8];
            #pragma unroll
            for (int m = 0; m < 4; ++m)
                acc2[m][nt] = __builtin_amdgcn_mfma_f32_16x16x32_bf16(a[m], bf, acc2[m][nt], 0, 0, 0);
        }
    }

    // ---- BN2 + max over k (16 cols per tile, 2 tiles per point) + ReLU ----
    #pragma unroll
    for (int m = 0; m < 4; ++m) {
        int rb = wr + m * 16 + lq * 4;
        float s0 = sBN[2][rb], s1 = sBN[2][rb + 1], s2 = sBN[2][rb + 2], s3 = sBN[2][rb + 3];
        float h0 = sBN[3][rb], h1 = sBN[3][rb + 1], h2 = sBN[3][rb + 2], h3 = sBN[3][rb + 3];
        #pragma unroll
        for (int lp = 0; lp < 2; ++lp) {       // 2 points per wave
            int n = n0 + (w >> 1) * 2 + lp;
            float v0 = fmaxf(fmaf(acc2[m][2 * lp][0],     s0, h0), fmaf(acc2[m][2 * lp + 1][0], s0, h0));
            float v1 = fmaxf(fmaf(acc2[m][2 * lp][1],     s1, h1), fmaf(acc2[m][2 * lp + 1][1], s1, h1));
            float v2 = fmaxf(fmaf(acc2[m][2 * lp][2],     s2, h2), fmaf(acc2[m][2 * lp + 1][2], s2, h2));
            float v3 = fmaxf(fmaf(acc2[m][2 * lp][3],     s3, h3), fmaf(acc2[m][2 * lp + 1][3], s3, h3));
            #pragma unroll
            for (int st = 1; st <= 8; st <<= 1) {
                v0 = fmaxf(v0, __shfl_xor(v0, st, 64));
                v1 = fmaxf(v1, __shfl_xor(v1, st, 64));
                v2 = fmaxf(v2, __shfl_xor(v2, st, 64));
                v3 = fmaxf(v3, __shfl_xor(v3, st, 64));
            }
            if (lr == 0) {
                out[((size_t)(b * C2_ + rb))     * N_ + n] = fmaxf(v0, 0.f);
                out[((size_t)(b * C2_ + rb + 1)) * N_ + n] = fmaxf(v1, 0.f);
                out[((size_t)(b * C2_ + rb + 2)) * N_ + n] = fmaxf(v2, 0.f);
                out[((size_t)(b * C2_ + rb + 3)) * N_ + n] = fmaxf(v3, 0.f);
            }
        }
    }
}

extern "C" void kernel_launch(void* const* d_in, const int* in_sizes, int n_in,
                              void* d_out, int out_size, void* d_ws, size_t ws_size,
                              hipStream_t stream) {
    const float* p   = (const float*)d_in[0];
    const float* f   = (const float*)d_in[1];
    const float* W1  = (const float*)d_in[2];
    const float* g1  = (const float*)d_in[3];
    const float* bb1 = (const float*)d_in[4];
    const float* m1  = (const float*)d_in[5];
    const float* v1  = (const float*)d_in[6];
    const float* W2  = (const float*)d_in[7];
    const float* g2  = (const float*)d_in[8];
    const float* bb2 = (const float*)d_in[9];
    const float* m2  = (const float*)d_in[10];
    const float* v2  = (const float*)d_in[11];
    float* out = (float*)d_out;

    char* ws = (char*)d_ws;
    int*   idxbuf = (int*)ws;                          // 2 MB
    short* fT     = (short*)(ws + (2 << 20));          // 2 MB
    short* W1p    = (short*)(ws + (4 << 20));          // 24 KB
    short* W2p    = (short*)(ws + (4 << 20) + 0x6000); // 32 KB
    float* bnv    = (float*)(ws + (4 << 20) + 0xE000); // 2 KB

    weight_prep_kernel<<<1, 128, 0, stream>>>(W1, g1, bb1, m1, v1,
                                              W2, g2, bb2, m2, v2,
                                              W1p, W2p, bnv);
    transpose_f_kernel<<<(B_ * N_) / 256, 256, 0, stream>>>(f, fT);
    ball_query_kernel<<<(B_ * N_ * 64) / 256, 256, 0, stream>>>(p, idxbuf);
    fused_mfma_kernel<<<(B_ * N_) / 4, 256, 0, stream>>>(p, idxbuf, fT, W1p, W2p, bnv, out);
}